// Round 9
// baseline (479.710 us; speedup 1.0000x reference)
//
#include <hip/hip_runtime.h>
#include <hip/hip_bf16.h>

// ---------------------------------------------------------------------------
// RNN_17214228922840: GraphRNN-ish model. fp32 I/O, bf16 MFMA compute.
//   B=128, TV=32, TE=64, VOCAB=1024, EMB=256, H=512 (3H=1536), REPR=128, NET=8
// Outputs (flat, fp32): O_vertex [128,1024,32] | O_edge [128,32,2,64] | O_edge_type [128,8,64]
// h row space b-major: row = b*T + t.   gi row space t-major: row = t*128 + b.
// gi produced INSIDE the scan kernel by producer blocks (agent-scope stores),
// consumed per-t behind gicnt flags -> gi GEMMs leave the critical path.
// ---------------------------------------------------------------------------

typedef __bf16 bf16_t;
typedef bf16_t bf16x8 __attribute__((ext_vector_type(8)));
typedef bf16_t bf16x4 __attribute__((ext_vector_type(4)));
typedef float  f32x4  __attribute__((ext_vector_type(4)));

// workspace layout (bf16 element offsets)
#define OFF_GIV  0ull                    // 4096*1536 (t-major)
#define OFF_GIE  6291456ull              // 8192*1536 (t-major)
#define OFF_HV   18874368ull             // 128*32*512 (b-major)
#define OFF_HE   20971520ull             // 128*64*512 (b-major)
#define OFF_VREP 25165824ull             // 128*32*128
#define OFF_EREP 25690112ull             // 128*64*128
#define OFF_HBUF 26738688ull             // 16 slots * 2 parity * 8192
#define FLAG_BYTE_OFF 54001664ull        // 16 slots * 4 ints (poison 0xAA < 1 = self-reset)
#define GICNT_BYTE_OFF 54001920ull       // 96 ints (zeroed by prep)
#define OFF_CVT  27002880ull             // converted bf16 weights below
#define CVT_VEMB  0ull
#define CVT_EEMB  262144ull
#define CVT_VWI   270336ull
#define CVT_EWI   663552ull
#define CVT_VWH   1449984ull
#define CVT_EWH   2236416ull
#define CVT_VOUT  3022848ull
#define CVT_VREPW 3547136ull
#define CVT_EREPW 3612672ull

// output flat offsets (fp32 elements)
#define OUT_OV 0ull
#define OUT_OE 4194304ull
#define OUT_OT 4718592ull

__device__ __forceinline__ float fsigmoid(float x) {
    float e = __builtin_amdgcn_exp2f(-x * 1.4426950408889634f);
    return __builtin_amdgcn_rcpf(1.0f + e);
}
__device__ __forceinline__ float ftanh(float x) {
    x = fminf(x, 15.0f);
    float e = __builtin_amdgcn_exp2f(x * 2.8853900817779268f); // exp(2x)
    return (e - 1.0f) * __builtin_amdgcn_rcpf(e + 1.0f);
}

// ---------------------------------------------------------------------------
// prep: fp32 -> bf16 downcast of weights/embeddings (3592 blocks x 1024 elem)
// + block 3592 zeroes the 96 gi counters (must reach MALL: dispatch-end
// release writes back L2 -> visible to the fused kernel's agent-scope polls).
// ---------------------------------------------------------------------------
__global__ __launch_bounds__(256) void prep_kernel(
    const float* __restrict__ vemb, const float* __restrict__ eemb,
    const float* __restrict__ vwi,  const float* __restrict__ ewi,
    const float* __restrict__ vwh,  const float* __restrict__ ewh,
    const float* __restrict__ voutw, const float* __restrict__ vrepw,
    const float* __restrict__ erepw, bf16_t* __restrict__ cvt,
    int* __restrict__ gicnt)
{
    int blk = blockIdx.x;
    if (blk >= 3592) {
        if (threadIdx.x < 96) gicnt[threadIdx.x] = 0;
        return;
    }
    const float* src; bf16_t* dst; int lb;
    if (blk < 256)       { src = vemb;  dst = cvt + CVT_VEMB;  lb = blk; }
    else if (blk < 264)  { src = eemb;  dst = cvt + CVT_EEMB;  lb = blk - 256; }
    else if (blk < 648)  { src = vwi;   dst = cvt + CVT_VWI;   lb = blk - 264; }
    else if (blk < 1416) { src = ewi;   dst = cvt + CVT_EWI;   lb = blk - 648; }
    else if (blk < 2184) { src = vwh;   dst = cvt + CVT_VWH;   lb = blk - 1416; }
    else if (blk < 2952) { src = ewh;   dst = cvt + CVT_EWH;   lb = blk - 2184; }
    else if (blk < 3464) { src = voutw; dst = cvt + CVT_VOUT;  lb = blk - 2952; }
    else if (blk < 3528) { src = vrepw; dst = cvt + CVT_VREPW; lb = blk - 3464; }
    else                 { src = erepw; dst = cvt + CVT_EREPW; lb = blk - 3528; }
    int idx = lb * 1024 + threadIdx.x * 4;
    float4 v = *(const float4*)(src + idx);
    bf16x4 o;
    o[0] = (bf16_t)v.x; o[1] = (bf16_t)v.y; o[2] = (bf16_t)v.z; o[3] = (bf16_t)v.w;
    *(bf16x4*)(dst + idx) = o;
}

// ---------------------------------------------------------------------------
// gi producer tile: 512-thread block (8 waves x 64x64), rows t-major
// (row = t*128 + b; 512 rows = 4 t-slices). Writes gi with AGENT-scope 2B
// stores (MALL -> cross-XCD visible), then waitcnt + barrier + 4 counter adds.
// GATHER 1 = vertex emb (K=256), 2 = edge emb pair (K=512).
// ---------------------------------------------------------------------------
template<int GATHER, int K>
__device__ __forceinline__ void produce_gi(
    const bf16_t* __restrict__ W, const float* __restrict__ bias,
    bf16_t* __restrict__ C, const int* __restrict__ gidx,
    const bf16_t* __restrict__ emb, int* __restrict__ cnt, int bx, int nbase)
{
    constexpr int K32 = K / 32;
    const int tid = threadIdx.x, lane = tid & 63, wv = tid >> 6;
    const int r16 = lane & 15, quad = lane >> 4, koff = quad * 8;
    const int mbase = bx * 512 + wv * 64;

    const bf16_t* ap0[4];
    const bf16_t* ap1[4];
#pragma unroll
    for (int i = 0; i < 4; ++i) {
        int row = mbase + i * 16 + r16;
        int b = row & 127, t = row >> 7;
        if (GATHER == 1) {
            ap0[i] = emb + (size_t)gidx[b * 32 + t] * 256 + koff;
            ap1[i] = ap0[i];
        } else {
            int c = (b * 64 + t) * 3;
            ap0[i] = emb + (size_t)gidx[c] * 256 + koff;
            ap1[i] = emb + (size_t)gidx[c + 1] * 256 + koff;
        }
    }
    const bf16_t* bp[4];
#pragma unroll
    for (int j = 0; j < 4; ++j)
        bp[j] = W + (size_t)(nbase + j * 16 + r16) * K + koff;

    f32x4 acc[4][4];
#pragma unroll
    for (int i = 0; i < 4; ++i)
#pragma unroll
        for (int j = 0; j < 4; ++j) acc[i][j] = (f32x4){0.f, 0.f, 0.f, 0.f};

    for (int kc = 0; kc < K32; ++kc) {
        bf16x8 a[4], b[4];
#pragma unroll
        for (int i = 0; i < 4; ++i) {
            const bf16_t* p;
            if (GATHER == 2) p = (kc < 8) ? (ap0[i] + kc * 32) : (ap1[i] + (kc - 8) * 32);
            else             p = ap0[i] + kc * 32;
            a[i] = *(const bf16x8*)p;
        }
#pragma unroll
        for (int j = 0; j < 4; ++j) b[j] = *(const bf16x8*)(bp[j] + kc * 32);
#pragma unroll
        for (int i = 0; i < 4; ++i)
#pragma unroll
            for (int j = 0; j < 4; ++j)
                acc[i][j] = __builtin_amdgcn_mfma_f32_16x16x32_bf16(a[i], b[j], acc[i][j], 0, 0, 0);
    }

#pragma unroll
    for (int j = 0; j < 4; ++j) {
        int col = nbase + j * 16 + r16;
        float bf = bias[col];
#pragma unroll
        for (int i = 0; i < 4; ++i) {
#pragma unroll
            for (int q = 0; q < 4; ++q) {
                int row = mbase + i * 16 + quad * 4 + q;
                bf16_t hb = (bf16_t)(acc[i][j][q] + bf);
                __hip_atomic_store((unsigned short*)(C + (size_t)row * 1536 + col),
                                   __builtin_bit_cast(unsigned short, hb),
                                   __ATOMIC_RELAXED, __HIP_MEMORY_SCOPE_AGENT);
            }
        }
    }
    __builtin_amdgcn_s_waitcnt(0);
    __syncthreads();
    if (tid < 4)
        __hip_atomic_fetch_add(&cnt[bx * 4 + tid], 1,
                               __ATOMIC_RELAXED, __HIP_MEMORY_SCOPE_AGENT);
}

// ---------------------------------------------------------------------------
// Fused scan + gi producers (single launch).
// Blocks 0..63: GRU scan (dispatched first -> co-resident). 64..255: giV
// producers (8 x 24). 256..639: giE producers (16 x 24).
// GRU step t gates on gicnt[role][t] >= 24 (24 col-blocks per t-slice) before
// loading gi; h exchange protocol unchanged from R7.
// ---------------------------------------------------------------------------
__global__ __launch_bounds__(512) void fused_scan(
    bf16_t* __restrict__ giV, bf16_t* __restrict__ giE,
    const bf16_t* __restrict__ WhV, const bf16_t* __restrict__ WhE,
    const float* __restrict__ bhV, const float* __restrict__ bhE,
    bf16_t* __restrict__ hV, bf16_t* __restrict__ hE,
    bf16_t* __restrict__ hbuf, int* __restrict__ flags, int* __restrict__ gicnt,
    const int* __restrict__ ivtx, const int* __restrict__ iedg,
    const bf16_t* __restrict__ vemb, const bf16_t* __restrict__ eemb,
    const bf16_t* __restrict__ vwi, const bf16_t* __restrict__ ewi,
    const float* __restrict__ vbi, const float* __restrict__ ebi)
{
    __shared__ __align__(16) bf16_t hbf[2][16][520];
    const int bid = blockIdx.x;

    if (bid >= 64) {
        if (bid < 256) {            // giV producers
            int g2 = bid - 64;
            produce_gi<1, 256>(vwi, vbi, giV, ivtx, vemb, gicnt, g2 & 7, (g2 >> 3) * 64);
        } else {                    // giE producers
            int g3 = bid - 256;
            produce_gi<2, 512>(ewi, ebi, giE, iedg, eemb, gicnt + 32, g3 & 15, (g3 >> 4) * 64);
        }
        return;
    }

    // ---- GRU ----
    const int role = bid >> 5;          // 0 vertex, 1 edge
    const int lb   = bid & 31;
    const int g    = lb & 7;            // batch group
    const int s    = lb >> 3;           // col-slice 0..3
    const bf16_t* gi = role ? giE : giV;
    const bf16_t* Wh = role ? WhE : WhV;
    const float*  bh = role ? bhE : bhV;
    bf16_t* hout = role ? hE : hV;
    const int T = role ? 64 : 32;
    const int slot = role * 8 + g;
    bf16_t* buf0 = hbuf + (size_t)slot * 2 * 8192;
    int* fl = flags + slot * 4;
    int* gc = role ? (gicnt + 32) : gicnt;
    const int bb = g * 16;

    const int tid = threadIdx.x, lane = tid & 63, wv = tid >> 6;
    const int r16 = lane & 15, quad = lane >> 4, koff = quad * 8;
    const int j = s * 128 + wv * 16 + r16;   // this lane's h column (0..511)
    const int rs0 = (s + 1) & 3, rs1 = (s + 2) & 3, rs2 = (s + 3) & 3;

    // --- Wh slice in registers: wfrag[gate][kc] (192 regs) ---
    bf16x8 wfrag[3][16];
#pragma unroll
    for (int gate = 0; gate < 3; ++gate) {
        const bf16_t* wrow = Wh + ((size_t)(gate * 512 + j)) * 512 + koff;
#pragma unroll
        for (int kc = 0; kc < 16; ++kc)
            wfrag[gate][kc] = *(const bf16x8*)(wrow + kc * 32);
    }
    const float bhr = bh[j], bhz = bh[512 + j], bhn = bh[1024 + j];
    float hq[4] = {0.f, 0.f, 0.f, 0.f};

    for (int i = tid; i < 16 * 512; i += 512)
        hbf[0][i >> 9][i & 511] = (bf16_t)0.f;   // h(0)=0; ordered by first barrier

    const int arow = tid >> 5, au = tid & 31;    // phase-A unit: row 0..15, 8B unit 0..31

    for (int t = 0; t < T; ++t) {
        // gate on gi[t] availability (24 producer col-blocks), then load gi
        while (__hip_atomic_load(&gc[t], __ATOMIC_RELAXED,
                                 __HIP_MEMORY_SCOPE_AGENT) < 24) { }
        asm volatile("" ::: "memory");
        // gi (t-major): 12 scalar loads; results not needed until phase C
        float gv[3][4];
#pragma unroll
        for (int gg = 0; gg < 3; ++gg)
#pragma unroll
            for (int q = 0; q < 4; ++q)
                gv[gg][q] = (float)gi[((size_t)(t * 128 + bb + quad * 4 + q)) * 1536
                                      + gg * 512 + j];

        if (t > 0) {
            // acquire: poll the 4 per-block flags (one 16B segment per iter)
            while (!__all((int)(__hip_atomic_load(&fl[lane & 3], __ATOMIC_RELAXED,
                                                  __HIP_MEMORY_SCOPE_AGENT) >= t))) { }
            asm volatile("" ::: "memory");
            // remote 3 slices of h(t) -> LDS parity t&1 (own slice already there)
            unsigned long long* src = (unsigned long long*)(buf0 + (size_t)(t & 1) * 8192);
            unsigned long long vv[3];
            vv[0] = __hip_atomic_load(src + arow * 128 + rs0 * 32 + au, __ATOMIC_RELAXED, __HIP_MEMORY_SCOPE_AGENT);
            vv[1] = __hip_atomic_load(src + arow * 128 + rs1 * 32 + au, __ATOMIC_RELAXED, __HIP_MEMORY_SCOPE_AGENT);
            vv[2] = __hip_atomic_load(src + arow * 128 + rs2 * 32 + au, __ATOMIC_RELAXED, __HIP_MEMORY_SCOPE_AGENT);
            *(unsigned long long*)&hbf[t & 1][arow][rs0 * 128 + au * 4] = vv[0];
            *(unsigned long long*)&hbf[t & 1][arow][rs1 * 128 + au * 4] = vv[1];
            *(unsigned long long*)&hbf[t & 1][arow][rs2 * 128 + au * 4] = vv[2];
        }
        __syncthreads();

        // MFMA: gh for this lane's 16-col strip, 3 gates
        const bf16_t (*cur)[520] = hbf[t & 1];
        f32x4 ar = {0.f,0.f,0.f,0.f}, az = {0.f,0.f,0.f,0.f}, an = {0.f,0.f,0.f,0.f};
#pragma unroll
        for (int kc = 0; kc < 16; ++kc) {
            bf16x8 a = *(const bf16x8*)&cur[r16][kc * 32 + koff];
            ar = __builtin_amdgcn_mfma_f32_16x16x32_bf16(a, wfrag[0][kc], ar, 0, 0, 0);
            az = __builtin_amdgcn_mfma_f32_16x16x32_bf16(a, wfrag[1][kc], az, 0, 0, 0);
            an = __builtin_amdgcn_mfma_f32_16x16x32_bf16(a, wfrag[2][kc], an, 0, 0, 0);
        }

        // gates + h update (C-frag: col=lane&15, row=quad*4+q)
        bf16_t hb4[4];
#pragma unroll
        for (int q = 0; q < 4; ++q) {
            float r = fsigmoid(gv[0][q] + ar[q] + bhr);
            float z = fsigmoid(gv[1][q] + az[q] + bhz);
            float n = ftanh(gv[2][q] + r * (an[q] + bhn));
            float hnew = (1.0f - z) * n + z * hq[q];
            hq[q] = hnew;
            hb4[q] = (bf16_t)hnew;
        }

        // own slice of h(t+1) -> next-parity LDS (never round-trips MALL)
        bf16_t (*nxt)[520] = hbf[(t + 1) & 1];
#pragma unroll
        for (int q = 0; q < 4; ++q) nxt[quad * 4 + q][j] = hb4[q];

        if (t + 1 < T) {
            // release: h(t+1) remote-visible via MALL, drain, barrier, flag
            bf16_t* dstg = buf0 + (size_t)((t + 1) & 1) * 8192;
#pragma unroll
            for (int q = 0; q < 4; ++q)
                __hip_atomic_store((unsigned short*)(dstg + (quad * 4 + q) * 512 + j),
                                   __builtin_bit_cast(unsigned short, hb4[q]),
                                   __ATOMIC_RELAXED, __HIP_MEMORY_SCOPE_AGENT);
            __builtin_amdgcn_s_waitcnt(0);
            __syncthreads();
            if (tid == 0)
                __hip_atomic_store(&fl[s], t + 1,
                                   __ATOMIC_RELAXED, __HIP_MEMORY_SCOPE_AGENT);
        } else {
            __syncthreads();
        }
        // hout (HBM) after the flag: latency overlaps the next poll
#pragma unroll
        for (int q = 0; q < 4; ++q)
            hout[((size_t)((bb + quad * 4 + q) * T + t)) * 512 + j] = hb4[q];
    }
}

// ---------------------------------------------------------------------------
// Post-scan GEMM: C = A @ W^T + bias. Wave computes 64x64 (4x4 MFMA tiles).
// Rows b-major: row = b*TT + t.
// OUTMODE: 0 row-major C[row*N+col]; 1 O_vertex float4 at [(b*1024+col)*32+t]
// ---------------------------------------------------------------------------
template<int OUTMODE, int K, int TT, typename CT>
__global__ __launch_bounds__(256) void gemm_bt(
    const bf16_t* __restrict__ A, const bf16_t* __restrict__ W,
    const float* __restrict__ bias, CT* __restrict__ C, int N)
{
    constexpr int K32 = K / 32;
    const int tid = threadIdx.x, lane = tid & 63, wv = tid >> 6;
    const int r16 = lane & 15, quad = lane >> 4, koff = quad * 8;
    const int mbase = blockIdx.x * 256 + wv * 64;
    const int nbase = blockIdx.y * 64;

    const bf16_t* ap0[4];
#pragma unroll
    for (int i = 0; i < 4; ++i)
        ap0[i] = A + (size_t)(mbase + i * 16 + r16) * K + koff;
    const bf16_t* bp[4];
#pragma unroll
    for (int j = 0; j < 4; ++j)
        bp[j] = W + (size_t)(nbase + j * 16 + r16) * K + koff;

    f32x4 acc[4][4];
#pragma unroll
    for (int i = 0; i < 4; ++i)
#pragma unroll
        for (int j = 0; j < 4; ++j) acc[i][j] = (f32x4){0.f, 0.f, 0.f, 0.f};

    for (int kc = 0; kc < K32; ++kc) {
        bf16x8 a[4], b[4];
#pragma unroll
        for (int i = 0; i < 4; ++i) a[i] = *(const bf16x8*)(ap0[i] + kc * 32);
#pragma unroll
        for (int j = 0; j < 4; ++j) b[j] = *(const bf16x8*)(bp[j] + kc * 32);
#pragma unroll
        for (int i = 0; i < 4; ++i)
#pragma unroll
            for (int j = 0; j < 4; ++j)
                acc[i][j] = __builtin_amdgcn_mfma_f32_16x16x32_bf16(a[i], b[j], acc[i][j], 0, 0, 0);
    }

#pragma unroll
    for (int j = 0; j < 4; ++j) {
        int col = nbase + j * 16 + r16;
        float bf = bias[col];
#pragma unroll
        for (int i = 0; i < 4; ++i) {
            int rowq = mbase + i * 16 + quad * 4;
            if (OUTMODE == 1) {
                int b = rowq >> 5, t0 = rowq & 31;
                float4 v4;
                v4.x = acc[i][j][0] + bf; v4.y = acc[i][j][1] + bf;
                v4.z = acc[i][j][2] + bf; v4.w = acc[i][j][3] + bf;
                *(float4*)((float*)C + ((size_t)(b * 1024) + col) * 32 + t0) = v4;
            } else {
#pragma unroll
                for (int q = 0; q < 4; ++q)
                    C[(size_t)(rowq + q) * N + col] = (CT)(acc[i][j][q] + bf);
            }
        }
    }
}

// O_edge_type[b,k,te] = erep[b,te,:] . etype_W[k,:] + etype_b[k]
__global__ __launch_bounds__(256) void etype_kernel(
    const bf16_t* __restrict__ erep, const float* __restrict__ W,
    const float* __restrict__ bias, float* __restrict__ out)
{
    int o = blockIdx.x * 256 + threadIdx.x;      // 65536 outputs
    int te = o & 63, k = (o >> 6) & 7, b = o >> 9;
    float sacc = bias[k];
    const bf16_t* e = erep + ((size_t)(b * 64 + te)) * 128;
    const float* w = W + k * 128;
#pragma unroll 8
    for (int r = 0; r < 128; ++r) sacc += (float)e[r] * w[r];
    out[OUT_OT + o] = sacc;
}

// O_edge[b,tv,{0,1},te] = sum_r tanh(e[b,te,r]+v[b,tv,r]) * {src,dst}_w[r] + b
__global__ __launch_bounds__(256) void attn_kernel(
    const bf16_t* __restrict__ erep, const bf16_t* __restrict__ vrep,
    const float* __restrict__ src_w, const float* __restrict__ src_b,
    const float* __restrict__ dst_w, const float* __restrict__ dst_b,
    float* __restrict__ out)
{
    int b = blockIdx.x >> 1, half = blockIdx.x & 1;
    __shared__ float es[32][129], vs[32][129], swf[128], dwf[128];
    int tid = threadIdx.x;
    for (int f = tid; f < 32 * 128; f += 256) {
        int i = f >> 7, r = f & 127;
        es[i][r] = (float)erep[((size_t)(b * 64 + half * 32 + i)) * 128 + r];
        vs[i][r] = (float)vrep[((size_t)(b * 32 + i)) * 128 + r];
    }
    if (tid < 128) { swf[tid] = src_w[tid]; dwf[tid] = dst_w[tid]; }
    __syncthreads();
    float sb = src_b[0], db = dst_b[0];
    for (int p = tid; p < 1024; p += 256) {
        int te = p & 31, tv = p >> 5;
        float sacc = 0.f, dacc = 0.f;
#pragma unroll 4
        for (int r = 0; r < 128; ++r) {
            float u = ftanh(es[te][r] + vs[tv][r]);
            sacc += u * swf[r];
            dacc += u * dwf[r];
        }
        int teg = half * 32 + te;
        size_t base = OUT_OE + ((size_t)(b * 32 + tv) * 2) * 64;
        out[base + teg]      = sacc + sb;
        out[base + 64 + teg] = dacc + db;
    }
}

extern "C" void kernel_launch(void* const* d_in, const int* in_sizes, int n_in,
                              void* d_out, int out_size, void* d_ws, size_t ws_size,
                              hipStream_t stream)
{
    const int*   input_vertex = (const int*)d_in[0];
    const int*   input_edge   = (const int*)d_in[1];
    const float* vertex_emb   = (const float*)d_in[2];
    const float* v_Wi  = (const float*)d_in[3];
    const float* v_Wh  = (const float*)d_in[4];
    const float* v_bi  = (const float*)d_in[5];
    const float* v_bh  = (const float*)d_in[6];
    const float* vout_W = (const float*)d_in[7];
    const float* vout_b = (const float*)d_in[8];
    const float* vrep_W = (const float*)d_in[9];
    const float* vrep_b = (const float*)d_in[10];
    const float* edge_emb = (const float*)d_in[11];
    const float* e_Wi  = (const float*)d_in[12];
    const float* e_Wh  = (const float*)d_in[13];
    const float* e_bi  = (const float*)d_in[14];
    const float* e_bh  = (const float*)d_in[15];
    const float* erep_W = (const float*)d_in[16];
    const float* erep_b = (const float*)d_in[17];
    const float* etype_W = (const float*)d_in[18];
    const float* etype_b = (const float*)d_in[19];
    const float* src_w = (const float*)d_in[20];
    const float* src_b = (const float*)d_in[21];
    const float* dst_w = (const float*)d_in[22];
    const float* dst_b = (const float*)d_in[23];

    bf16_t* ws   = (bf16_t*)d_ws;
    bf16_t* giV  = ws + OFF_GIV;
    bf16_t* giE  = ws + OFF_GIE;
    bf16_t* hV   = ws + OFF_HV;
    bf16_t* hE   = ws + OFF_HE;
    bf16_t* vrep = ws + OFF_VREP;
    bf16_t* erep = ws + OFF_EREP;
    bf16_t* hbuf = ws + OFF_HBUF;
    bf16_t* cvt  = ws + OFF_CVT;
    int*    flags = (int*)((char*)d_ws + FLAG_BYTE_OFF);
    int*    gicnt = (int*)((char*)d_ws + GICNT_BYTE_OFF);
    float*  out  = (float*)d_out;

    // downcast weights to bf16 + zero gi counters (h-flags self-init: 0xAA<1)
    prep_kernel<<<3593, 256, 0, stream>>>(vertex_emb, edge_emb, v_Wi, e_Wi, v_Wh, e_Wh,
                                          vout_W, vrep_W, erep_W, cvt, gicnt);

    // fused: GRU scans (blocks 0..63) + gi producers (64..639), pipelined per-t
    fused_scan<<<640, 512, 0, stream>>>(
        giV, giE, cvt + CVT_VWH, cvt + CVT_EWH, v_bh, e_bh, hV, hE,
        hbuf, flags, gicnt, input_vertex, input_edge,
        cvt + CVT_VEMB, cvt + CVT_EEMB, cvt + CVT_VWI, cvt + CVT_EWI,
        v_bi, e_bi);

    // output projections (rows b-major)
    gemm_bt<1, 512, 32, float><<<dim3(16, 16), 256, 0, stream>>>(
        hV, cvt + CVT_VOUT, vout_b, out, 1024);
    gemm_bt<0, 512, 32, bf16_t><<<dim3(16, 2), 256, 0, stream>>>(
        hV, cvt + CVT_VREPW, vrep_b, vrep, 128);
    gemm_bt<0, 512, 64, bf16_t><<<dim3(32, 2), 256, 0, stream>>>(
        hE, cvt + CVT_EREPW, erep_b, erep, 128);

    etype_kernel<<<256, 256, 0, stream>>>(erep, etype_W, etype_b, out);
    attn_kernel<<<256, 256, 0, stream>>>(erep, vrep, src_w, src_b, dst_w, dst_b, out);
}

// Round 10
// 456.037 us; speedup vs baseline: 1.0519x; 1.0519x over previous
//
#include <hip/hip_runtime.h>
#include <hip/hip_bf16.h>

// ---------------------------------------------------------------------------
// RNN_17214228922840: GraphRNN-ish model. fp32 I/O, bf16 MFMA compute.
//   B=128, TV=32, TE=64, VOCAB=1024, EMB=256, H=512 (3H=1536), REPR=128, NET=8
// Outputs (flat, fp32): O_vertex [128,1024,32] | O_edge [128,32,2,64] | O_edge_type [128,8,64]
// h row space b-major: row = b*T + t.   gi row space t-major: row = t*128 + b.
// Single fused kernel: gru blocks (0..63) + gi producers (64..639) +
// OV/vrep consumers gated on vdone (640..783) + erep consumers on edone
// (784..815). LDS padded to 65KB -> 2 blocks/CU (producer interference halved).
// Cross-XCD handoffs all use the validated pattern: agent-scope stores ->
// s_waitcnt(0) -> counter add (agent); consumer polls counter then normal
// first-touch loads.
// ---------------------------------------------------------------------------

typedef __bf16 bf16_t;
typedef bf16_t bf16x8 __attribute__((ext_vector_type(8)));
typedef bf16_t bf16x4 __attribute__((ext_vector_type(4)));
typedef float  f32x4  __attribute__((ext_vector_type(4)));

// workspace layout (bf16 element offsets)
#define OFF_GIV  0ull                    // 4096*1536 (t-major)
#define OFF_GIE  6291456ull              // 8192*1536 (t-major)
#define OFF_HV   18874368ull             // 128*32*512 (b-major)
#define OFF_HE   20971520ull             // 128*64*512 (b-major)
#define OFF_VREP 25165824ull             // 128*32*128
#define OFF_EREP 25690112ull             // 128*64*128
#define OFF_HBUF 26738688ull             // 16 slots * 2 parity * 8192
#define FLAG_BYTE_OFF 54001664ull        // 16 slots * 4 ints (poison 0xAA < 1 = self-reset)
#define GICNT_BYTE_OFF 54001920ull       // 128 ints: [0..95] gi slices, [96]=vdone, [97]=edone
#define OFF_CVT  27002880ull             // converted bf16 weights below
#define CVT_VEMB  0ull
#define CVT_EEMB  262144ull
#define CVT_VWI   270336ull
#define CVT_EWI   663552ull
#define CVT_VWH   1449984ull
#define CVT_EWH   2236416ull
#define CVT_VOUT  3022848ull
#define CVT_VREPW 3547136ull
#define CVT_EREPW 3612672ull

// output flat offsets (fp32 elements)
#define OUT_OV 0ull
#define OUT_OE 4194304ull
#define OUT_OT 4718592ull

__device__ __forceinline__ float fsigmoid(float x) {
    float e = __builtin_amdgcn_exp2f(-x * 1.4426950408889634f);
    return __builtin_amdgcn_rcpf(1.0f + e);
}
__device__ __forceinline__ float ftanh(float x) {
    x = fminf(x, 15.0f);
    float e = __builtin_amdgcn_exp2f(x * 2.8853900817779268f); // exp(2x)
    return (e - 1.0f) * __builtin_amdgcn_rcpf(e + 1.0f);
}

// ---------------------------------------------------------------------------
// prep: fp32 -> bf16 downcast of weights/embeddings (3592 blocks x 1024 elem)
// + block 3592 zeroes the 128 pipeline counters.
// ---------------------------------------------------------------------------
__global__ __launch_bounds__(256) void prep_kernel(
    const float* __restrict__ vemb, const float* __restrict__ eemb,
    const float* __restrict__ vwi,  const float* __restrict__ ewi,
    const float* __restrict__ vwh,  const float* __restrict__ ewh,
    const float* __restrict__ voutw, const float* __restrict__ vrepw,
    const float* __restrict__ erepw, bf16_t* __restrict__ cvt,
    int* __restrict__ gicnt)
{
    int blk = blockIdx.x;
    if (blk >= 3592) {
        if (threadIdx.x < 128) gicnt[threadIdx.x] = 0;
        return;
    }
    const float* src; bf16_t* dst; int lb;
    if (blk < 256)       { src = vemb;  dst = cvt + CVT_VEMB;  lb = blk; }
    else if (blk < 264)  { src = eemb;  dst = cvt + CVT_EEMB;  lb = blk - 256; }
    else if (blk < 648)  { src = vwi;   dst = cvt + CVT_VWI;   lb = blk - 264; }
    else if (blk < 1416) { src = ewi;   dst = cvt + CVT_EWI;   lb = blk - 648; }
    else if (blk < 2184) { src = vwh;   dst = cvt + CVT_VWH;   lb = blk - 1416; }
    else if (blk < 2952) { src = ewh;   dst = cvt + CVT_EWH;   lb = blk - 2184; }
    else if (blk < 3464) { src = voutw; dst = cvt + CVT_VOUT;  lb = blk - 2952; }
    else if (blk < 3528) { src = vrepw; dst = cvt + CVT_VREPW; lb = blk - 3464; }
    else                 { src = erepw; dst = cvt + CVT_EREPW; lb = blk - 3528; }
    int idx = lb * 1024 + threadIdx.x * 4;
    float4 v = *(const float4*)(src + idx);
    bf16x4 o;
    o[0] = (bf16_t)v.x; o[1] = (bf16_t)v.y; o[2] = (bf16_t)v.z; o[3] = (bf16_t)v.w;
    *(bf16x4*)(dst + idx) = o;
}

// ---------------------------------------------------------------------------
// gi producer tile: 8 waves x 64x64, rows t-major (row = t*128 + b). Agent
// stores -> waitcnt -> barrier -> 4 slice-counter adds.
// ---------------------------------------------------------------------------
template<int GATHER, int K>
__device__ __forceinline__ void produce_gi(
    const bf16_t* __restrict__ W, const float* __restrict__ bias,
    bf16_t* __restrict__ C, const int* __restrict__ gidx,
    const bf16_t* __restrict__ emb, int* __restrict__ cnt, int bx, int nbase)
{
    constexpr int K32 = K / 32;
    const int tid = threadIdx.x, lane = tid & 63, wv = tid >> 6;
    const int r16 = lane & 15, quad = lane >> 4, koff = quad * 8;
    const int mbase = bx * 512 + wv * 64;

    const bf16_t* ap0[4];
    const bf16_t* ap1[4];
#pragma unroll
    for (int i = 0; i < 4; ++i) {
        int row = mbase + i * 16 + r16;
        int b = row & 127, t = row >> 7;
        if (GATHER == 1) {
            ap0[i] = emb + (size_t)gidx[b * 32 + t] * 256 + koff;
            ap1[i] = ap0[i];
        } else {
            int c = (b * 64 + t) * 3;
            ap0[i] = emb + (size_t)gidx[c] * 256 + koff;
            ap1[i] = emb + (size_t)gidx[c + 1] * 256 + koff;
        }
    }
    const bf16_t* bp[4];
#pragma unroll
    for (int j = 0; j < 4; ++j)
        bp[j] = W + (size_t)(nbase + j * 16 + r16) * K + koff;

    f32x4 acc[4][4];
#pragma unroll
    for (int i = 0; i < 4; ++i)
#pragma unroll
        for (int j = 0; j < 4; ++j) acc[i][j] = (f32x4){0.f, 0.f, 0.f, 0.f};

    for (int kc = 0; kc < K32; ++kc) {
        bf16x8 a[4], b[4];
#pragma unroll
        for (int i = 0; i < 4; ++i) {
            const bf16_t* p;
            if (GATHER == 2) p = (kc < 8) ? (ap0[i] + kc * 32) : (ap1[i] + (kc - 8) * 32);
            else             p = ap0[i] + kc * 32;
            a[i] = *(const bf16x8*)p;
        }
#pragma unroll
        for (int j = 0; j < 4; ++j) b[j] = *(const bf16x8*)(bp[j] + kc * 32);
#pragma unroll
        for (int i = 0; i < 4; ++i)
#pragma unroll
            for (int j = 0; j < 4; ++j)
                acc[i][j] = __builtin_amdgcn_mfma_f32_16x16x32_bf16(a[i], b[j], acc[i][j], 0, 0, 0);
    }

#pragma unroll
    for (int j = 0; j < 4; ++j) {
        int col = nbase + j * 16 + r16;
        float bf = bias[col];
#pragma unroll
        for (int i = 0; i < 4; ++i) {
#pragma unroll
            for (int q = 0; q < 4; ++q) {
                int row = mbase + i * 16 + quad * 4 + q;
                bf16_t hb = (bf16_t)(acc[i][j][q] + bf);
                __hip_atomic_store((unsigned short*)(C + (size_t)row * 1536 + col),
                                   __builtin_bit_cast(unsigned short, hb),
                                   __ATOMIC_RELAXED, __HIP_MEMORY_SCOPE_AGENT);
            }
        }
    }
    __builtin_amdgcn_s_waitcnt(0);
    __syncthreads();
    if (tid < 4)
        __hip_atomic_fetch_add(&cnt[bx * 4 + tid], 1,
                               __ATOMIC_RELAXED, __HIP_MEMORY_SCOPE_AGENT);
}

// ---------------------------------------------------------------------------
// consumer GEMM tile: 8 waves x 64x64, 512 rows per block, A via normal loads
// (first touch after the done-counter gate). OUTMODE 0: bf16 row-major [N];
// OUTMODE 1: O_vertex float4 at [(b*1024+col)*32 + t].
// ---------------------------------------------------------------------------
template<int OUTMODE, int K>
__device__ __forceinline__ void consume_gemm(
    const bf16_t* __restrict__ A, const bf16_t* __restrict__ W,
    const float* __restrict__ bias, void* __restrict__ Cv,
    int N, int bx, int nbase)
{
    constexpr int K32 = K / 32;
    const int tid = threadIdx.x, lane = tid & 63, wv = tid >> 6;
    const int r16 = lane & 15, quad = lane >> 4, koff = quad * 8;
    const int mbase = bx * 512 + wv * 64;

    const bf16_t* ap[4];
#pragma unroll
    for (int i = 0; i < 4; ++i)
        ap[i] = A + (size_t)(mbase + i * 16 + r16) * K + koff;
    const bf16_t* bp[4];
#pragma unroll
    for (int j = 0; j < 4; ++j)
        bp[j] = W + (size_t)(nbase + j * 16 + r16) * K + koff;

    f32x4 acc[4][4];
#pragma unroll
    for (int i = 0; i < 4; ++i)
#pragma unroll
        for (int j = 0; j < 4; ++j) acc[i][j] = (f32x4){0.f, 0.f, 0.f, 0.f};

    for (int kc = 0; kc < K32; ++kc) {
        bf16x8 a[4], b[4];
#pragma unroll
        for (int i = 0; i < 4; ++i) a[i] = *(const bf16x8*)(ap[i] + kc * 32);
#pragma unroll
        for (int j = 0; j < 4; ++j) b[j] = *(const bf16x8*)(bp[j] + kc * 32);
#pragma unroll
        for (int i = 0; i < 4; ++i)
#pragma unroll
            for (int j = 0; j < 4; ++j)
                acc[i][j] = __builtin_amdgcn_mfma_f32_16x16x32_bf16(a[i], b[j], acc[i][j], 0, 0, 0);
    }

#pragma unroll
    for (int j = 0; j < 4; ++j) {
        int col = nbase + j * 16 + r16;
        float bf = bias[col];
#pragma unroll
        for (int i = 0; i < 4; ++i) {
            int rowq = mbase + i * 16 + quad * 4;
            if (OUTMODE == 1) {
                int b = rowq >> 5, t0 = rowq & 31;
                float4 v4;
                v4.x = acc[i][j][0] + bf; v4.y = acc[i][j][1] + bf;
                v4.z = acc[i][j][2] + bf; v4.w = acc[i][j][3] + bf;
                *(float4*)((float*)Cv + ((size_t)(b * 1024) + col) * 32 + t0) = v4;
            } else {
                bf16_t* C = (bf16_t*)Cv;
#pragma unroll
                for (int q = 0; q < 4; ++q)
                    C[(size_t)(rowq + q) * N + col] = (bf16_t)(acc[i][j][q] + bf);
            }
        }
    }
}

// ---------------------------------------------------------------------------
// Fused pipeline kernel.
// ---------------------------------------------------------------------------
__global__ __launch_bounds__(512) void fused_scan(
    bf16_t* __restrict__ giV, bf16_t* __restrict__ giE,
    const bf16_t* __restrict__ WhV, const bf16_t* __restrict__ WhE,
    const float* __restrict__ bhV, const float* __restrict__ bhE,
    bf16_t* __restrict__ hV, bf16_t* __restrict__ hE,
    bf16_t* __restrict__ hbuf, int* __restrict__ flags, int* __restrict__ gicnt,
    const int* __restrict__ ivtx, const int* __restrict__ iedg,
    const bf16_t* __restrict__ vemb, const bf16_t* __restrict__ eemb,
    const bf16_t* __restrict__ vwi, const bf16_t* __restrict__ ewi,
    const float* __restrict__ vbi, const float* __restrict__ ebi,
    const bf16_t* __restrict__ voutw, const float* __restrict__ voutb,
    const bf16_t* __restrict__ vrepw, const float* __restrict__ vrepb,
    const bf16_t* __restrict__ erepw, const float* __restrict__ erepb,
    bf16_t* __restrict__ vrep, bf16_t* __restrict__ erep,
    float* __restrict__ out)
{
    __shared__ __align__(16) bf16_t hbf[2][16][520];
    __shared__ char ldspad[31744];          // pad LDS to 65KB -> 2 blocks/CU
    const int bid = blockIdx.x;
    if ((int)gridDim.x < 0) ldspad[threadIdx.x] = 0;   // keep allocation

    if (bid >= 64) {
        if (bid < 256) {            // giV producers
            int g2 = bid - 64;
            produce_gi<1, 256>(vwi, vbi, giV, ivtx, vemb, gicnt, g2 & 7, (g2 >> 3) * 64);
        } else if (bid < 640) {     // giE producers
            int g3 = bid - 256;
            produce_gi<2, 512>(ewi, ebi, giE, iedg, eemb, gicnt + 32, g3 & 15, (g3 >> 4) * 64);
        } else if (bid < 784) {     // OV (128) + vrep (16) consumers: gate vdone==32
            while (__hip_atomic_load(&gicnt[96], __ATOMIC_RELAXED,
                                     __HIP_MEMORY_SCOPE_AGENT) < 32)
                __builtin_amdgcn_s_sleep(8);
            asm volatile("" ::: "memory");
            if (bid < 768) {
                int cb = bid - 640;
                consume_gemm<1, 512>(hV, voutw, voutb, out, 1024, cb & 7, (cb >> 3) * 64);
            } else {
                int cb = bid - 768;
                consume_gemm<0, 512>(hV, vrepw, vrepb, vrep, 128, cb & 7, (cb >> 3) * 64);
            }
        } else {                    // erep consumers (32): gate edone==32
            while (__hip_atomic_load(&gicnt[97], __ATOMIC_RELAXED,
                                     __HIP_MEMORY_SCOPE_AGENT) < 32)
                __builtin_amdgcn_s_sleep(8);
            asm volatile("" ::: "memory");
            int cb = bid - 784;
            consume_gemm<0, 512>(hE, erepw, erepb, erep, 128, cb & 15, (cb >> 4) * 64);
        }
        return;
    }

    // ---- GRU (blocks 0..63) ----
    const int role = bid >> 5;          // 0 vertex, 1 edge
    const int lb   = bid & 31;
    const int g    = lb & 7;            // batch group
    const int s    = lb >> 3;           // col-slice 0..3
    const bf16_t* gi = role ? giE : giV;
    const bf16_t* Wh = role ? WhE : WhV;
    const float*  bh = role ? bhE : bhV;
    bf16_t* hout = role ? hE : hV;
    const int T = role ? 64 : 32;
    const int slot = role * 8 + g;
    bf16_t* buf0 = hbuf + (size_t)slot * 2 * 8192;
    int* fl = flags + slot * 4;
    int* gc = role ? (gicnt + 32) : gicnt;
    int* done = role ? &gicnt[97] : &gicnt[96];
    const int bb = g * 16;

    const int tid = threadIdx.x, lane = tid & 63, wv = tid >> 6;
    const int r16 = lane & 15, quad = lane >> 4, koff = quad * 8;
    const int j = s * 128 + wv * 16 + r16;   // this lane's h column (0..511)
    const int rs0 = (s + 1) & 3, rs1 = (s + 2) & 3, rs2 = (s + 3) & 3;

    // --- Wh slice in registers: wfrag[gate][kc] (192 regs) ---
    bf16x8 wfrag[3][16];
#pragma unroll
    for (int gate = 0; gate < 3; ++gate) {
        const bf16_t* wrow = Wh + ((size_t)(gate * 512 + j)) * 512 + koff;
#pragma unroll
        for (int kc = 0; kc < 16; ++kc)
            wfrag[gate][kc] = *(const bf16x8*)(wrow + kc * 32);
    }
    const float bhr = bh[j], bhz = bh[512 + j], bhn = bh[1024 + j];
    float hq[4] = {0.f, 0.f, 0.f, 0.f};

    for (int i = tid; i < 16 * 512; i += 512)
        hbf[0][i >> 9][i & 511] = (bf16_t)0.f;   // h(0)=0; ordered by first barrier

    const int arow = tid >> 5, au = tid & 31;    // phase-A unit: row 0..15, 8B unit 0..31

    for (int t = 0; t < T; ++t) {
        // gate on gi[t] availability (24 producer col-blocks), then load gi
        while (__hip_atomic_load(&gc[t], __ATOMIC_RELAXED,
                                 __HIP_MEMORY_SCOPE_AGENT) < 24) { }
        asm volatile("" ::: "memory");
        float gv[3][4];
#pragma unroll
        for (int gg = 0; gg < 3; ++gg)
#pragma unroll
            for (int q = 0; q < 4; ++q)
                gv[gg][q] = (float)gi[((size_t)(t * 128 + bb + quad * 4 + q)) * 1536
                                      + gg * 512 + j];

        if (t > 0) {
            // acquire: poll the 4 per-block flags (one 16B segment per iter)
            while (!__all((int)(__hip_atomic_load(&fl[lane & 3], __ATOMIC_RELAXED,
                                                  __HIP_MEMORY_SCOPE_AGENT) >= t))) { }
            asm volatile("" ::: "memory");
            // remote 3 slices of h(t) -> LDS parity t&1 (own slice already there)
            unsigned long long* src = (unsigned long long*)(buf0 + (size_t)(t & 1) * 8192);
            unsigned long long vv[3];
            vv[0] = __hip_atomic_load(src + arow * 128 + rs0 * 32 + au, __ATOMIC_RELAXED, __HIP_MEMORY_SCOPE_AGENT);
            vv[1] = __hip_atomic_load(src + arow * 128 + rs1 * 32 + au, __ATOMIC_RELAXED, __HIP_MEMORY_SCOPE_AGENT);
            vv[2] = __hip_atomic_load(src + arow * 128 + rs2 * 32 + au, __ATOMIC_RELAXED, __HIP_MEMORY_SCOPE_AGENT);
            *(unsigned long long*)&hbf[t & 1][arow][rs0 * 128 + au * 4] = vv[0];
            *(unsigned long long*)&hbf[t & 1][arow][rs1 * 128 + au * 4] = vv[1];
            *(unsigned long long*)&hbf[t & 1][arow][rs2 * 128 + au * 4] = vv[2];
        }
        __syncthreads();

        // MFMA: gh for this lane's 16-col strip, 3 gates
        const bf16_t (*cur)[520] = hbf[t & 1];
        f32x4 ar = {0.f,0.f,0.f,0.f}, az = {0.f,0.f,0.f,0.f}, an = {0.f,0.f,0.f,0.f};
#pragma unroll
        for (int kc = 0; kc < 16; ++kc) {
            bf16x8 a = *(const bf16x8*)&cur[r16][kc * 32 + koff];
            ar = __builtin_amdgcn_mfma_f32_16x16x32_bf16(a, wfrag[0][kc], ar, 0, 0, 0);
            az = __builtin_amdgcn_mfma_f32_16x16x32_bf16(a, wfrag[1][kc], az, 0, 0, 0);
            an = __builtin_amdgcn_mfma_f32_16x16x32_bf16(a, wfrag[2][kc], an, 0, 0, 0);
        }

        // gates + h update (C-frag: col=lane&15, row=quad*4+q)
        bf16_t hb4[4];
#pragma unroll
        for (int q = 0; q < 4; ++q) {
            float r = fsigmoid(gv[0][q] + ar[q] + bhr);
            float z = fsigmoid(gv[1][q] + az[q] + bhz);
            float n = ftanh(gv[2][q] + r * (an[q] + bhn));
            float hnew = (1.0f - z) * n + z * hq[q];
            hq[q] = hnew;
            hb4[q] = (bf16_t)hnew;
        }

        // own slice of h(t+1) -> next-parity LDS (never round-trips MALL)
        bf16_t (*nxt)[520] = hbf[(t + 1) & 1];
#pragma unroll
        for (int q = 0; q < 4; ++q) nxt[quad * 4 + q][j] = hb4[q];

        if (t + 1 < T) {
            // release: h(t+1) remote-visible via MALL, drain, barrier, flag
            bf16_t* dstg = buf0 + (size_t)((t + 1) & 1) * 8192;
#pragma unroll
            for (int q = 0; q < 4; ++q)
                __hip_atomic_store((unsigned short*)(dstg + (quad * 4 + q) * 512 + j),
                                   __builtin_bit_cast(unsigned short, hb4[q]),
                                   __ATOMIC_RELAXED, __HIP_MEMORY_SCOPE_AGENT);
            __builtin_amdgcn_s_waitcnt(0);
            __syncthreads();
            if (tid == 0)
                __hip_atomic_store(&fl[s], t + 1,
                                   __ATOMIC_RELAXED, __HIP_MEMORY_SCOPE_AGENT);
        } else {
            __syncthreads();
        }
        // hout: AGENT stores (consumers read it inside this kernel), post-flag
#pragma unroll
        for (int q = 0; q < 4; ++q)
            __hip_atomic_store(
                (unsigned short*)(hout + ((size_t)((bb + quad * 4 + q) * T + t)) * 512 + j),
                __builtin_bit_cast(unsigned short, hb4[q]),
                __ATOMIC_RELAXED, __HIP_MEMORY_SCOPE_AGENT);
    }

    // signal scan completion (per role)
    __builtin_amdgcn_s_waitcnt(0);
    __syncthreads();
    if (tid == 0)
        __hip_atomic_fetch_add(done, 1, __ATOMIC_RELAXED, __HIP_MEMORY_SCOPE_AGENT);
}

// O_edge_type[b,k,te] = erep[b,te,:] . etype_W[k,:] + etype_b[k]
__global__ __launch_bounds__(256) void etype_kernel(
    const bf16_t* __restrict__ erep, const float* __restrict__ W,
    const float* __restrict__ bias, float* __restrict__ out)
{
    int o = blockIdx.x * 256 + threadIdx.x;      // 65536 outputs
    int te = o & 63, k = (o >> 6) & 7, b = o >> 9;
    float sacc = bias[k];
    const bf16_t* e = erep + ((size_t)(b * 64 + te)) * 128;
    const float* w = W + k * 128;
#pragma unroll 8
    for (int r = 0; r < 128; ++r) sacc += (float)e[r] * w[r];
    out[OUT_OT + o] = sacc;
}

// O_edge[b,tv,{0,1},te] = sum_r tanh(e[b,te,r]+v[b,tv,r]) * {src,dst}_w[r] + b
__global__ __launch_bounds__(256) void attn_kernel(
    const bf16_t* __restrict__ erep, const bf16_t* __restrict__ vrep,
    const float* __restrict__ src_w, const float* __restrict__ src_b,
    const float* __restrict__ dst_w, const float* __restrict__ dst_b,
    float* __restrict__ out)
{
    int b = blockIdx.x >> 1, half = blockIdx.x & 1;
    __shared__ float es[32][129], vs[32][129], swf[128], dwf[128];
    int tid = threadIdx.x;
    for (int f = tid; f < 32 * 128; f += 256) {
        int i = f >> 7, r = f & 127;
        es[i][r] = (float)erep[((size_t)(b * 64 + half * 32 + i)) * 128 + r];
        vs[i][r] = (float)vrep[((size_t)(b * 32 + i)) * 128 + r];
    }
    if (tid < 128) { swf[tid] = src_w[tid]; dwf[tid] = dst_w[tid]; }
    __syncthreads();
    float sb = src_b[0], db = dst_b[0];
    for (int p = tid; p < 1024; p += 256) {
        int te = p & 31, tv = p >> 5;
        float sacc = 0.f, dacc = 0.f;
#pragma unroll 4
        for (int r = 0; r < 128; ++r) {
            float u = ftanh(es[te][r] + vs[tv][r]);
            sacc += u * swf[r];
            dacc += u * dwf[r];
        }
        int teg = half * 32 + te;
        size_t base = OUT_OE + ((size_t)(b * 32 + tv) * 2) * 64;
        out[base + teg]      = sacc + sb;
        out[base + 64 + teg] = dacc + db;
    }
}

extern "C" void kernel_launch(void* const* d_in, const int* in_sizes, int n_in,
                              void* d_out, int out_size, void* d_ws, size_t ws_size,
                              hipStream_t stream)
{
    const int*   input_vertex = (const int*)d_in[0];
    const int*   input_edge   = (const int*)d_in[1];
    const float* vertex_emb   = (const float*)d_in[2];
    const float* v_Wi  = (const float*)d_in[3];
    const float* v_Wh  = (const float*)d_in[4];
    const float* v_bi  = (const float*)d_in[5];
    const float* v_bh  = (const float*)d_in[6];
    const float* vout_W = (const float*)d_in[7];
    const float* vout_b = (const float*)d_in[8];
    const float* vrep_W = (const float*)d_in[9];
    const float* vrep_b = (const float*)d_in[10];
    const float* edge_emb = (const float*)d_in[11];
    const float* e_Wi  = (const float*)d_in[12];
    const float* e_Wh  = (const float*)d_in[13];
    const float* e_bi  = (const float*)d_in[14];
    const float* e_bh  = (const float*)d_in[15];
    const float* erep_W = (const float*)d_in[16];
    const float* erep_b = (const float*)d_in[17];
    const float* etype_W = (const float*)d_in[18];
    const float* etype_b = (const float*)d_in[19];
    const float* src_w = (const float*)d_in[20];
    const float* src_b = (const float*)d_in[21];
    const float* dst_w = (const float*)d_in[22];
    const float* dst_b = (const float*)d_in[23];

    bf16_t* ws   = (bf16_t*)d_ws;
    bf16_t* giV  = ws + OFF_GIV;
    bf16_t* giE  = ws + OFF_GIE;
    bf16_t* hV   = ws + OFF_HV;
    bf16_t* hE   = ws + OFF_HE;
    bf16_t* vrep = ws + OFF_VREP;
    bf16_t* erep = ws + OFF_EREP;
    bf16_t* hbuf = ws + OFF_HBUF;
    bf16_t* cvt  = ws + OFF_CVT;
    int*    flags = (int*)((char*)d_ws + FLAG_BYTE_OFF);
    int*    gicnt = (int*)((char*)d_ws + GICNT_BYTE_OFF);
    float*  out  = (float*)d_out;

    // downcast weights to bf16 + zero pipeline counters
    prep_kernel<<<3593, 256, 0, stream>>>(vertex_emb, edge_emb, v_Wi, e_Wi, v_Wh, e_Wh,
                                          vout_W, vrep_W, erep_W, cvt, gicnt);

    // fused pipeline: scans + gi producers + OV/vrep/erep consumers
    fused_scan<<<816, 512, 0, stream>>>(
        giV, giE, cvt + CVT_VWH, cvt + CVT_EWH, v_bh, e_bh, hV, hE,
        hbuf, flags, gicnt, input_vertex, input_edge,
        cvt + CVT_VEMB, cvt + CVT_EEMB, cvt + CVT_VWI, cvt + CVT_EWI,
        v_bi, e_bi,
        cvt + CVT_VOUT, vout_b, cvt + CVT_VREPW, vrep_b,
        cvt + CVT_EREPW, erep_b, vrep, erep, out);

    etype_kernel<<<256, 256, 0, stream>>>(erep, etype_W, etype_b, out);
    attn_kernel<<<256, 256, 0, stream>>>(erep, vrep, src_w, src_b, dst_w, dst_b, out);
}